// Round 17
// baseline (519.744 us; speedup 1.0000x reference)
//
#include <hip/hip_runtime.h>
#include <hip/hip_bf16.h>
#include <hip/hip_cooperative_groups.h>

namespace cg = cooperative_groups;

#define H 4
#define C 64
#define HC 256
#define FIN 128
#define FE 32
#define NCLS 16
#define BN_EPS 1e-5f
#define WCOLS 960   // 256 q | 256 k | 256 v | 128 qWe | 64 skip

typedef __hip_bfloat16 bf16;
typedef __attribute__((ext_vector_type(8))) short short8v;
typedef __attribute__((ext_vector_type(4))) short short4v;
typedef __attribute__((ext_vector_type(2))) short short2v;
typedef __attribute__((ext_vector_type(4))) float floatx4;

__device__ __forceinline__ float b2f(bf16 v) { return __bfloat162float(v); }
__device__ __forceinline__ float bs2f(short s) {
    unsigned u = ((unsigned)(unsigned short)s) << 16;
    return __uint_as_float(u);
}
__device__ __forceinline__ short f2bs(float f) {
    bf16 h = __float2bfloat16(f);
    return *reinterpret_cast<short*>(&h);
}

// ------- pack: Wt[960][128] bf16 + bias[960] + Wet[64][128] + Wct[16][64] + BN scale/shift -------
__global__ __launch_bounds__(128) void pack_w_kernel(
    const float* __restrict__ Wq, const float* __restrict__ Wk, const float* __restrict__ Wv,
    const float* __restrict__ We, const float* __restrict__ Wskip,
    const float* __restrict__ bq, const float* __restrict__ bk, const float* __restrict__ bv,
    const float* __restrict__ bskip,
    const float* __restrict__ gamma, const float* __restrict__ beta,
    const float* __restrict__ rmean, const float* __restrict__ rvar,
    const float* __restrict__ Wc,
    short* __restrict__ Wt, float* __restrict__ bias,
    short* __restrict__ Wet, short* __restrict__ Wct,
    float* __restrict__ scalev, float* __restrict__ shiftv)
{
    const int bid = blockIdx.x;
    const int t = threadIdx.x;       // 0..127
    if (bid < WCOLS) {
        const int col = bid;
        float val, b = 0.f;
        if (col < 256)      { val = Wq[t * HC + col]; b = bq[col]; }
        else if (col < 512) { val = Wk[t * HC + col - 256]; b = bk[col - 256]; }
        else if (col < 768) { val = Wv[t * HC + col - 512]; b = bv[col - 512]; }
        else if (col < 896) {
            int j = col - 768, h = j >> 5, f = j & 31;
            float acc = 0.f;
#pragma unroll 8
            for (int c = 0; c < C; ++c) acc += Wq[t * HC + h * C + c] * We[f * HC + h * C + c];
            val = acc;
            acc = 0.f;
            for (int c = 0; c < C; ++c) acc += bq[h * C + c] * We[f * HC + h * C + c];
            b = acc;
        }
        else { int c2 = col - 896; val = Wskip[t * C + c2]; b = bskip[c2]; }
        Wt[(size_t)col * FIN + t] = f2bs(val);
        if (t == 0) bias[col] = b;
    } else if (bid < WCOLS + 64) {
        const int c2 = bid - WCOLS;
        const int f = t & 31, h = t >> 5;
        Wet[(size_t)c2 * FIN + t] = f2bs(We[f * HC + h * C + c2]);
    } else if (bid < WCOLS + 64 + NCLS) {
        const int cls = bid - WCOLS - 64;
        if (t < C) Wct[(size_t)cls * C + t] = f2bs(Wc[t * NCLS + cls]);
    } else {
        if (t < C) {
            float inv = rsqrtf(rvar[t] + BN_EPS);
            float sc = gamma[t] * inv;
            scalev[t] = sc;
            shiftv[t] = beta[t] - rmean[t] * sc;
        }
    }
}

// ------- MFMA: [N,128] x Wt[960,128]^T ; 32 rows/block (R12 proven structure) -------
// + fused hist epilogue (grid-stride over E; independent work, hides in qkv's idle pipes)
__global__ __launch_bounds__(256) void qkv_mfma_kernel(
    const float* __restrict__ x, const short* __restrict__ Wt,
    const float* __restrict__ bias,
    bf16* __restrict__ q, unsigned char* __restrict__ kv,
    bf16* __restrict__ qWe, bf16* __restrict__ skip,
    const int* __restrict__ dst, int* __restrict__ deg, int N, int E)
{
    const int wid = threadIdx.x >> 6;
    const int lane = threadIdx.x & 63;
    const int n0 = blockIdx.x * 32;
    const int arow = lane & 15, agrp = lane >> 4;
    __shared__ __align__(16) unsigned char kvs[32][512];

    short8v afrag[2][4];
#pragma unroll
    for (int rt = 0; rt < 2; ++rt) {
        int nA = n0 + rt * 16 + arow; if (nA >= N) nA = N - 1;
        const float* xrow = x + (size_t)nA * FIN + agrp * 8;
#pragma unroll
        for (int ks = 0; ks < 4; ++ks) {
            floatx4 x0 = *(const floatx4*)(xrow + ks * 32);
            floatx4 x1 = *(const floatx4*)(xrow + ks * 32 + 4);
            short8v a;
            a[0] = f2bs(x0[0]); a[1] = f2bs(x0[1]); a[2] = f2bs(x0[2]); a[3] = f2bs(x0[3]);
            a[4] = f2bs(x1[0]); a[5] = f2bs(x1[1]); a[6] = f2bs(x1[2]); a[7] = f2bs(x1[3]);
            afrag[rt][ks] = a;
        }
    }

    for (int ct = wid; ct < WCOLS / 16; ct += 4) {
        const int col0 = ct * 16;
        const int col = col0 + arow;
        const short* wp = Wt + (size_t)col * FIN + agrp * 8;
        short8v bfr[4];
#pragma unroll
        for (int ks = 0; ks < 4; ++ks) bfr[ks] = *(const short8v*)(wp + ks * 32);
        floatx4 acc0 = {0.f, 0.f, 0.f, 0.f};
        floatx4 acc1 = {0.f, 0.f, 0.f, 0.f};
#pragma unroll
        for (int ks = 0; ks < 4; ++ks) {
            acc0 = __builtin_amdgcn_mfma_f32_16x16x32_bf16(afrag[0][ks], bfr[ks], acc0, 0, 0, 0);
            acc1 = __builtin_amdgcn_mfma_f32_16x16x32_bf16(afrag[1][ks], bfr[ks], acc1, 0, 0, 0);
        }
        const float bb = bias[col];
#pragma unroll
        for (int rt = 0; rt < 2; ++rt) {
            const floatx4 acc = rt ? acc1 : acc0;
#pragma unroll
            for (int r = 0; r < 4; ++r) {
                const int row = rt * 16 + agrp * 4 + r;
                const int n = n0 + row;
                const float val = acc[r] + bb;
                if (col0 >= 256 && col0 < 768) {
                    int c = col - 256;
                    const int isv = (c >= 256) ? 4 : 0;
                    c &= 255;
                    const int pos = ((c >> 6) * 16 + ((c & 63) >> 2)) * 8 + (c & 3) + isv;
                    const int p8 = __builtin_amdgcn_cvt_pk_fp8_f32(val, val, 0, false);
                    kvs[row][pos] = (unsigned char)(p8 & 0xff);
                } else if (n < N) {
                    if (col0 < 256)      q[(size_t)n * HC + col]          = __float2bfloat16(val);
                    else if (col0 < 896) qWe[(size_t)n * 128 + col - 768] = __float2bfloat16(val);
                    else                 skip[(size_t)n * C + col - 896]  = __float2bfloat16(val);
                }
            }
        }
    }
    __syncthreads();
    // stream the 16KB kv tile out coalesced: 1024 x 16B chunks
    const int t = threadIdx.x;
#pragma unroll
    for (int it = 0; it < 4; ++it) {
        const int lin = it * 256 + t;      // 0..1023
        const int row = lin >> 5;          // 0..31
        const int ch  = lin & 31;          // 16B chunk within row
        const int n = n0 + row;
        if (n < N)
            *(uint4*)(kv + (size_t)n * 512 + ch * 16) = *(const uint4*)(&kvs[row][ch * 16]);
    }
    // fused hist: grid-stride over edges (independent of qkv outputs)
    const int gtid = blockIdx.x * 256 + t;
    const int nth = gridDim.x * 256;
    for (int i = gtid; i < E; i += nth) atomicAdd(&deg[dst[i]], 1);
}

// ------- cooperative CSR build: partial -> scan -> rowptr -> scatter, ONE launch -------
__global__ __launch_bounds__(256) void csr_kernel(
    const int* __restrict__ src, const int* __restrict__ dst,
    const int* __restrict__ deg, int* __restrict__ partials,
    int* __restrict__ rowptr, int* __restrict__ cnt2,
    int2* __restrict__ edg, int N, int E)
{
    cg::grid_group grid = cg::this_grid();
    const int t = threadIdx.x;
    const int nb = (N + 1023) >> 10;
    __shared__ int ws[4];
    __shared__ int sm[256];

    // phase 1: per-block partial sums (blocks 0..nb-1)
    if ((int)blockIdx.x < nb) {
        const int base = blockIdx.x * 1024 + t * 4;
        int s = 0;
#pragma unroll
        for (int i = 0; i < 4; ++i) {
            int idx = base + i;
            if (idx < N) s += deg[idx];
        }
#pragma unroll
        for (int off = 1; off < 64; off <<= 1) s += __shfl_xor(s, off, 64);
        if ((t & 63) == 0) ws[t >> 6] = s;
        __syncthreads();
        if (t == 0) partials[blockIdx.x] = ws[0] + ws[1] + ws[2] + ws[3];
    }
    grid.sync();

    // phase 2: block 0 scans the partials
    if (blockIdx.x == 0) {
        int v = (t < nb) ? partials[t] : 0;
        sm[t] = v;
        __syncthreads();
        for (int off = 1; off < 256; off <<= 1) {
            int vv = (t >= off) ? sm[t - off] : 0;
            __syncthreads();
            sm[t] += vv;
            __syncthreads();
        }
        if (t < nb) partials[t] = sm[t] - v;   // exclusive base per block
        if (t == 255) rowptr[N] = sm[255];     // grand total
    }
    grid.sync();

    // phase 3: write rowptr (blocks 0..nb-1)
    if ((int)blockIdx.x < nb) {
        const int base = blockIdx.x * 1024 + t * 4;
        int d[4];
        int s = 0;
#pragma unroll
        for (int i = 0; i < 4; ++i) {
            int idx = base + i;
            d[i] = (idx < N) ? deg[idx] : 0;
            s += d[i];
        }
        sm[t] = s;
        __syncthreads();
        for (int off = 1; off < 256; off <<= 1) {
            int vv = (t >= off) ? sm[t - off] : 0;
            __syncthreads();
            sm[t] += vv;
            __syncthreads();
        }
        int run = partials[blockIdx.x] + sm[t] - s;
#pragma unroll
        for (int i = 0; i < 4; ++i) {
            int idx = base + i;
            if (idx < N) { rowptr[idx] = run; run += d[i]; }
        }
    }
    grid.sync();

    // phase 4: scatter edge indices (grid-stride)
    const int gtid = blockIdx.x * 256 + t;
    const int nth = gridDim.x * 256;
    for (int i = gtid; i < E; i += nth) {
        const int d = dst[i];
        const int pos = rowptr[d] + atomicAdd(&cnt2[d], 1);
        edg[pos] = make_int2(src[i], i);
    }
}

// ------- fused per-node aggregation: fp8 kv, readlane broadcast, depth-2 pipeline -------
__global__ __launch_bounds__(256) void node_agg_kernel(
    const int2* __restrict__ edg, const int* __restrict__ rowptr,
    const float* __restrict__ ea,
    const bf16* __restrict__ q, const unsigned char* __restrict__ kv,
    const bf16* __restrict__ qWe,
    bf16* __restrict__ accV, bf16* __restrict__ aggEA, int N)
{
    const int w = threadIdx.x >> 6;
    const int lane = threadIdx.x & 63;
    const int d = blockIdx.x * 4 + w;
    if (d >= N) return;
    const int g = lane >> 4;     // head
    const int li = lane & 15;    // sub-lane: channels li*4..+3, features li*2..+1
    const int kvoff = (g * 16 + li) * 8;   // byte offset

    short4v qs = *(const short4v*)((const short*)q + (size_t)d * HC + g * C + li * 4);
    const float qv0 = bs2f(qs[0]), qv1 = bs2f(qs[1]), qv2 = bs2f(qs[2]), qv3 = bs2f(qs[3]);
    short2v qws = *(const short2v*)((const short*)qWe + (size_t)d * 128 + g * FE + li * 2);
    const float qw0 = bs2f(qws[0]), qw1 = bs2f(qws[1]);

    float den = 0.f;
    float a0 = 0.f, a1 = 0.f, a2 = 0.f, a3 = 0.f;
    float ag0 = 0.f, ag1 = 0.f;

    const int beg = rowptr[d];
    const int degc = rowptr[d + 1] - beg;

    for (int c0 = 0; c0 < degc; c0 += 64) {
        const int cnt = min(degc - c0, 64);
        int2 me = make_int2(0, 0);
        if (lane < cnt) me = edg[beg + c0 + lane];

        const int s0 = __builtin_amdgcn_readlane(me.x, 0);
        const int e0i = __builtin_amdgcn_readlane(me.y, 0);
        uint2 kvv = *(const uint2*)(kv + (size_t)s0 * 512 + kvoff);
        float2 eaf = *(const float2*)(ea + (size_t)e0i * FE + li * 2);

        for (int j = 0; j < cnt; ++j) {
            uint2 kvn = kvv; float2 ean = eaf;
            if (j + 1 < cnt) {
                const int sn = __builtin_amdgcn_readlane(me.x, j + 1);
                const int en = __builtin_amdgcn_readlane(me.y, j + 1);
                kvn = *(const uint2*)(kv + (size_t)sn * 512 + kvoff);
                ean = *(const float2*)(ea + (size_t)en * FE + li * 2);
            }
            const float ea0 = eaf.x, ea1 = eaf.y;
            const int klo = (int)kvv.x, vhi = (int)kvv.y;
            float p = qv0 * __builtin_amdgcn_cvt_f32_fp8(klo, 0)
                    + qv1 * __builtin_amdgcn_cvt_f32_fp8(klo, 1)
                    + qv2 * __builtin_amdgcn_cvt_f32_fp8(klo, 2)
                    + qv3 * __builtin_amdgcn_cvt_f32_fp8(klo, 3)
                    + qw0 * ea0 + qw1 * ea1;
            p += __shfl_xor(p, 1, 64);
            p += __shfl_xor(p, 2, 64);
            p += __shfl_xor(p, 4, 64);
            p += __shfl_xor(p, 8, 64);
            const float e = exp2f(p * 0.18033688f);  // exp(p/8)
            den += e;
            a0 += e * __builtin_amdgcn_cvt_f32_fp8(vhi, 0);
            a1 += e * __builtin_amdgcn_cvt_f32_fp8(vhi, 1);
            a2 += e * __builtin_amdgcn_cvt_f32_fp8(vhi, 2);
            a3 += e * __builtin_amdgcn_cvt_f32_fp8(vhi, 3);
            ag0 += e * ea0; ag1 += e * ea1;
            kvv = kvn; eaf = ean;
        }
    }

    const float inv = den > 0.f ? 0.25f / den : 0.f;
    a0 *= inv; a1 *= inv; a2 *= inv; a3 *= inv;
    a0 += __shfl_xor(a0, 16, 64); a0 += __shfl_xor(a0, 32, 64);
    a1 += __shfl_xor(a1, 16, 64); a1 += __shfl_xor(a1, 32, 64);
    a2 += __shfl_xor(a2, 16, 64); a2 += __shfl_xor(a2, 32, 64);
    a3 += __shfl_xor(a3, 16, 64); a3 += __shfl_xor(a3, 32, 64);
    if (g == 0) {
        short4v o;
        o[0] = f2bs(a0); o[1] = f2bs(a1); o[2] = f2bs(a2); o[3] = f2bs(a3);
        *(short4v*)((short*)accV + (size_t)d * C + li * 4) = o;
    }
    short2v so;
    so[0] = f2bs(ag0 * inv);
    so[1] = f2bs(ag1 * inv);
    *(short2v*)((short*)aggEA + (size_t)d * 128 + g * FE + li * 2) = so;
}

// ------- final: MFMA aggEA@Wet + epilogue + MFMA classifier -------
__global__ __launch_bounds__(256) void final_kernel(
    const bf16* __restrict__ aggEA, const bf16* __restrict__ accV,
    const bf16* __restrict__ skip,
    const short* __restrict__ Wet, const short* __restrict__ Wct,
    const float* __restrict__ scalev, const float* __restrict__ shiftv,
    const float* __restrict__ bc,
    float* __restrict__ out, int N)
{
    const int wid = threadIdx.x >> 6;
    const int lane = threadIdx.x & 63;
    const int n0 = blockIdx.x * 16;
    const int arow = lane & 15, agrp = lane >> 4;
    __shared__ short hs[16][72];   // bf16 h-tile, padded

    int nA = n0 + arow; if (nA >= N) nA = N - 1;
    const short* ap = (const short*)aggEA + (size_t)nA * 128 + agrp * 8;
    const int c0 = wid * 16;
    const int col = c0 + arow;
    const short* wp = Wet + (size_t)col * FIN + agrp * 8;
    floatx4 acc = {0.f, 0.f, 0.f, 0.f};
#pragma unroll
    for (int ks = 0; ks < 4; ++ks) {
        short8v a = *(const short8v*)(ap + ks * 32);
        short8v b = *(const short8v*)(wp + ks * 32);
        acc = __builtin_amdgcn_mfma_f32_16x16x32_bf16(a, b, acc, 0, 0, 0);
    }
    const float sc = scalev[col], sh = shiftv[col];
#pragma unroll
    for (int r = 0; r < 4; ++r) {
        const int row = agrp * 4 + r;
        int n = n0 + row; int nc = (n < N) ? n : (N - 1);
        float z = acc[r] + b2f(accV[(size_t)nc * C + col]) + b2f(skip[(size_t)nc * C + col]);
        z = fmaxf(z, 0.f);
        z = z * sc + sh;
        hs[row][col] = f2bs(z);
    }
    __syncthreads();

    if (wid == 0) {
        short8v ah[2], bh[2];
#pragma unroll
        for (int ks = 0; ks < 2; ++ks) {
#pragma unroll
            for (int j = 0; j < 8; ++j) ah[ks][j] = hs[arow][ks * 32 + agrp * 8 + j];
            bh[ks] = *(const short8v*)(Wct + (size_t)arow * C + ks * 32 + agrp * 8);
        }
        floatx4 co = {0.f, 0.f, 0.f, 0.f};
        co = __builtin_amdgcn_mfma_f32_16x16x32_bf16(ah[0], bh[0], co, 0, 0, 0);
        co = __builtin_amdgcn_mfma_f32_16x16x32_bf16(ah[1], bh[1], co, 0, 0, 0);
        const float bcv = bc[arow];
#pragma unroll
        for (int r = 0; r < 4; ++r) {
            const int n = n0 + agrp * 4 + r;
            if (n < N) out[(size_t)n * NCLS + arow] = co[r] + bcv;
        }
    }
}

extern "C" void kernel_launch(void* const* d_in, const int* in_sizes, int n_in,
                              void* d_out, int out_size, void* d_ws, size_t ws_size,
                              hipStream_t stream)
{
    const float* x     = (const float*)d_in[0];
    const int*   ei    = (const int*)d_in[1];
    const float* ea    = (const float*)d_in[2];
    const float* Wq    = (const float*)d_in[3];
    const float* bq    = (const float*)d_in[4];
    const float* Wk    = (const float*)d_in[5];
    const float* bk    = (const float*)d_in[6];
    const float* Wv    = (const float*)d_in[7];
    const float* bv    = (const float*)d_in[8];
    const float* We    = (const float*)d_in[9];
    const float* Wskip = (const float*)d_in[10];
    const float* bskip = (const float*)d_in[11];
    const float* gamma = (const float*)d_in[12];
    const float* beta  = (const float*)d_in[13];
    const float* rmean = (const float*)d_in[14];
    const float* rvar  = (const float*)d_in[15];
    const float* Wc    = (const float*)d_in[16];
    const float* bc    = (const float*)d_in[17];
    float* out = (float*)d_out;

    const int N = in_sizes[0] / FIN;
    const int E = in_sizes[2] / FE;
    const int* srcp = ei;
    const int* dstp = ei + E;

    char* w = (char*)d_ws;
    size_t off = 0;
    auto alloc = [&](size_t bytes) { void* p = w + off; off += (bytes + 255) & ~255ull; return p; };
    bf16*  qb     = (bf16*)alloc((size_t)N * HC * sizeof(bf16));
    unsigned char* kvbuf = (unsigned char*)alloc((size_t)N * 512);
    bf16*  qWe    = (bf16*)alloc((size_t)N * 128 * sizeof(bf16));
    bf16*  skip   = (bf16*)alloc((size_t)N * C * sizeof(bf16));
    int*   deg    = (int*)alloc((size_t)N * sizeof(int));
    int*   rowptr = (int*)alloc((size_t)(N + 1) * sizeof(int));
    int*   cnt2   = (int*)alloc((size_t)N * sizeof(int));
    int*   partials = (int*)alloc(256 * sizeof(int));
    int2*  edg    = (int2*)alloc((size_t)E * sizeof(int2));
    bf16*  accV   = (bf16*)alloc((size_t)N * C * sizeof(bf16));
    bf16*  aggEA  = (bf16*)alloc((size_t)N * 128 * sizeof(bf16));
    short* Wt     = (short*)alloc((size_t)WCOLS * FIN * sizeof(short));
    float* bias   = (float*)alloc((size_t)WCOLS * sizeof(float));
    short* Wet    = (short*)alloc((size_t)C * FIN * sizeof(short));
    short* Wct    = (short*)alloc((size_t)NCLS * C * sizeof(short));
    float* scalev = (float*)alloc((size_t)C * sizeof(float));
    float* shiftv = (float*)alloc((size_t)C * sizeof(float));

    hipMemsetAsync(deg,  0, (size_t)N * sizeof(int), stream);
    hipMemsetAsync(cnt2, 0, (size_t)N * sizeof(int), stream);

    pack_w_kernel<<<WCOLS + 64 + NCLS + 1, 128, 0, stream>>>(
        Wq, Wk, Wv, We, Wskip, bq, bk, bv, bskip, gamma, beta, rmean, rvar, Wc,
        Wt, bias, Wet, Wct, scalev, shiftv);
    qkv_mfma_kernel<<<(N + 31) / 32, 256, 0, stream>>>(
        x, Wt, bias, qb, kvbuf, qWe, skip, dstp, deg, N, E);

    {
        int Ni = N, Ei = E;
        void* args[] = { (void*)&srcp, (void*)&dstp, (void*)&deg, (void*)&partials,
                         (void*)&rowptr, (void*)&cnt2, (void*)&edg, (void*)&Ni, (void*)&Ei };
        hipLaunchCooperativeKernel((void*)csr_kernel, dim3(1024), dim3(256), args, 0, stream);
    }

    node_agg_kernel<<<(N + 3) / 4, 256, 0, stream>>>(edg, rowptr, ea, qb, kvbuf, qWe, accV, aggEA, N);
    final_kernel<<<(N + 15) / 16, 256, 0, stream>>>(aggEA, accV, skip, Wet, Wct, scalev, shiftv, bc, out, N);
}

// Round 18
// 190.015 us; speedup vs baseline: 2.7353x; 2.7353x over previous
//
#include <hip/hip_runtime.h>
#include <hip/hip_bf16.h>

#define H 4
#define C 64
#define HC 256
#define FIN 128
#define FE 32
#define NCLS 16
#define BN_EPS 1e-5f
#define WCOLS 960   // 256 q | 256 k | 256 v | 128 qWe | 64 skip

typedef __hip_bfloat16 bf16;
typedef __attribute__((ext_vector_type(8))) short short8v;
typedef __attribute__((ext_vector_type(4))) short short4v;
typedef __attribute__((ext_vector_type(2))) short short2v;
typedef __attribute__((ext_vector_type(4))) float floatx4;

__device__ __forceinline__ float b2f(bf16 v) { return __bfloat162float(v); }
__device__ __forceinline__ float bs2f(short s) {
    unsigned u = ((unsigned)(unsigned short)s) << 16;
    return __uint_as_float(u);
}
__device__ __forceinline__ short f2bs(float f) {
    bf16 h = __float2bfloat16(f);
    return *reinterpret_cast<short*>(&h);
}

// ------- pack: Wt[960][128] bf16 + bias[960] + Wet[64][128] + Wct[16][64] + BN scale/shift -------
__global__ __launch_bounds__(128) void pack_w_kernel(
    const float* __restrict__ Wq, const float* __restrict__ Wk, const float* __restrict__ Wv,
    const float* __restrict__ We, const float* __restrict__ Wskip,
    const float* __restrict__ bq, const float* __restrict__ bk, const float* __restrict__ bv,
    const float* __restrict__ bskip,
    const float* __restrict__ gamma, const float* __restrict__ beta,
    const float* __restrict__ rmean, const float* __restrict__ rvar,
    const float* __restrict__ Wc,
    short* __restrict__ Wt, float* __restrict__ bias,
    short* __restrict__ Wet, short* __restrict__ Wct,
    float* __restrict__ scalev, float* __restrict__ shiftv)
{
    const int bid = blockIdx.x;
    const int t = threadIdx.x;       // 0..127
    if (bid < WCOLS) {
        const int col = bid;
        float val, b = 0.f;
        if (col < 256)      { val = Wq[t * HC + col]; b = bq[col]; }
        else if (col < 512) { val = Wk[t * HC + col - 256]; b = bk[col - 256]; }
        else if (col < 768) { val = Wv[t * HC + col - 512]; b = bv[col - 512]; }
        else if (col < 896) {
            int j = col - 768, h = j >> 5, f = j & 31;
            float acc = 0.f;
#pragma unroll 8
            for (int c = 0; c < C; ++c) acc += Wq[t * HC + h * C + c] * We[f * HC + h * C + c];
            val = acc;
            acc = 0.f;
            for (int c = 0; c < C; ++c) acc += bq[h * C + c] * We[f * HC + h * C + c];
            b = acc;
        }
        else { int c2 = col - 896; val = Wskip[t * C + c2]; b = bskip[c2]; }
        Wt[(size_t)col * FIN + t] = f2bs(val);
        if (t == 0) bias[col] = b;
    } else if (bid < WCOLS + 64) {
        const int c2 = bid - WCOLS;
        const int f = t & 31, h = t >> 5;
        Wet[(size_t)c2 * FIN + t] = f2bs(We[f * HC + h * C + c2]);
    } else if (bid < WCOLS + 64 + NCLS) {
        const int cls = bid - WCOLS - 64;
        if (t < C) Wct[(size_t)cls * C + t] = f2bs(Wc[t * NCLS + cls]);
    } else {
        if (t < C) {
            float inv = rsqrtf(rvar[t] + BN_EPS);
            float sc = gamma[t] * inv;
            scalev[t] = sc;
            shiftv[t] = beta[t] - rmean[t] * sc;
        }
    }
}

// ------- MFMA: [N,128] x Wt[960,128]^T ; 32 rows/block (R12 proven structure) -------
// + fused hist epilogue (grid-stride over E; independent work, hides in qkv's idle pipes)
__global__ __launch_bounds__(256) void qkv_mfma_kernel(
    const float* __restrict__ x, const short* __restrict__ Wt,
    const float* __restrict__ bias,
    bf16* __restrict__ q, unsigned char* __restrict__ kv,
    bf16* __restrict__ qWe, bf16* __restrict__ skip,
    const int* __restrict__ dst, int* __restrict__ deg, int N, int E)
{
    const int wid = threadIdx.x >> 6;
    const int lane = threadIdx.x & 63;
    const int n0 = blockIdx.x * 32;
    const int arow = lane & 15, agrp = lane >> 4;
    __shared__ __align__(16) unsigned char kvs[32][512];

    short8v afrag[2][4];
#pragma unroll
    for (int rt = 0; rt < 2; ++rt) {
        int nA = n0 + rt * 16 + arow; if (nA >= N) nA = N - 1;
        const float* xrow = x + (size_t)nA * FIN + agrp * 8;
#pragma unroll
        for (int ks = 0; ks < 4; ++ks) {
            floatx4 x0 = *(const floatx4*)(xrow + ks * 32);
            floatx4 x1 = *(const floatx4*)(xrow + ks * 32 + 4);
            short8v a;
            a[0] = f2bs(x0[0]); a[1] = f2bs(x0[1]); a[2] = f2bs(x0[2]); a[3] = f2bs(x0[3]);
            a[4] = f2bs(x1[0]); a[5] = f2bs(x1[1]); a[6] = f2bs(x1[2]); a[7] = f2bs(x1[3]);
            afrag[rt][ks] = a;
        }
    }

    for (int ct = wid; ct < WCOLS / 16; ct += 4) {
        const int col0 = ct * 16;
        const int col = col0 + arow;
        const short* wp = Wt + (size_t)col * FIN + agrp * 8;
        short8v bfr[4];
#pragma unroll
        for (int ks = 0; ks < 4; ++ks) bfr[ks] = *(const short8v*)(wp + ks * 32);
        floatx4 acc0 = {0.f, 0.f, 0.f, 0.f};
        floatx4 acc1 = {0.f, 0.f, 0.f, 0.f};
#pragma unroll
        for (int ks = 0; ks < 4; ++ks) {
            acc0 = __builtin_amdgcn_mfma_f32_16x16x32_bf16(afrag[0][ks], bfr[ks], acc0, 0, 0, 0);
            acc1 = __builtin_amdgcn_mfma_f32_16x16x32_bf16(afrag[1][ks], bfr[ks], acc1, 0, 0, 0);
        }
        const float bb = bias[col];
#pragma unroll
        for (int rt = 0; rt < 2; ++rt) {
            const floatx4 acc = rt ? acc1 : acc0;
#pragma unroll
            for (int r = 0; r < 4; ++r) {
                const int row = rt * 16 + agrp * 4 + r;
                const int n = n0 + row;
                const float val = acc[r] + bb;
                if (col0 >= 256 && col0 < 768) {
                    int c = col - 256;
                    const int isv = (c >= 256) ? 4 : 0;
                    c &= 255;
                    const int pos = ((c >> 6) * 16 + ((c & 63) >> 2)) * 8 + (c & 3) + isv;
                    const int p8 = __builtin_amdgcn_cvt_pk_fp8_f32(val, val, 0, false);
                    kvs[row][pos] = (unsigned char)(p8 & 0xff);
                } else if (n < N) {
                    if (col0 < 256)      q[(size_t)n * HC + col]          = __float2bfloat16(val);
                    else if (col0 < 896) qWe[(size_t)n * 128 + col - 768] = __float2bfloat16(val);
                    else                 skip[(size_t)n * C + col - 896]  = __float2bfloat16(val);
                }
            }
        }
    }
    __syncthreads();
    // stream the 16KB kv tile out coalesced: 1024 x 16B chunks
    const int t = threadIdx.x;
#pragma unroll
    for (int it = 0; it < 4; ++it) {
        const int lin = it * 256 + t;      // 0..1023
        const int row = lin >> 5;          // 0..31
        const int ch  = lin & 31;          // 16B chunk within row
        const int n = n0 + row;
        if (n < N)
            *(uint4*)(kv + (size_t)n * 512 + ch * 16) = *(const uint4*)(&kvs[row][ch * 16]);
    }
    // fused hist: grid-stride over edges (independent of qkv outputs)
    const int gtid = blockIdx.x * 256 + t;
    const int nth = gridDim.x * 256;
    for (int i = gtid; i < E; i += nth) atomicAdd(&deg[dst[i]], 1);
}

// ------- CSR build (proven 4-kernel chain) -------
__global__ __launch_bounds__(256) void partial_kernel(
    const int* __restrict__ deg, int* __restrict__ partials, int N)
{
    const int t = threadIdx.x;
    const int base = blockIdx.x * 1024 + t * 4;
    int s = 0;
#pragma unroll
    for (int i = 0; i < 4; ++i) {
        int idx = base + i;
        if (idx < N) s += deg[idx];
    }
#pragma unroll
    for (int off = 1; off < 64; off <<= 1) s += __shfl_xor(s, off, 64);
    __shared__ int ws[4];
    if ((t & 63) == 0) ws[t >> 6] = s;
    __syncthreads();
    if (t == 0) partials[blockIdx.x] = ws[0] + ws[1] + ws[2] + ws[3];
}

__global__ __launch_bounds__(256) void scan_partials_kernel(
    int* __restrict__ partials, int* __restrict__ rowptr, int nb, int N)
{
    const int t = threadIdx.x;
    __shared__ int sm[256];
    int v = (t < nb) ? partials[t] : 0;
    sm[t] = v;
    __syncthreads();
    for (int off = 1; off < 256; off <<= 1) {
        int vv = (t >= off) ? sm[t - off] : 0;
        __syncthreads();
        sm[t] += vv;
        __syncthreads();
    }
    if (t < nb) partials[t] = sm[t] - v;   // exclusive base per block
    if (t == 255) rowptr[N] = sm[255];     // grand total
}

__global__ __launch_bounds__(256) void write_rowptr_kernel(
    const int* __restrict__ deg, const int* __restrict__ partials,
    int* __restrict__ rowptr, int N)
{
    const int t = threadIdx.x;
    const int base = blockIdx.x * 1024 + t * 4;
    int d[4];
    int s = 0;
#pragma unroll
    for (int i = 0; i < 4; ++i) {
        int idx = base + i;
        d[i] = (idx < N) ? deg[idx] : 0;
        s += d[i];
    }
    __shared__ int sm[256];
    sm[t] = s;
    __syncthreads();
    for (int off = 1; off < 256; off <<= 1) {
        int vv = (t >= off) ? sm[t - off] : 0;
        __syncthreads();
        sm[t] += vv;
        __syncthreads();
    }
    int run = partials[blockIdx.x] + sm[t] - s;
#pragma unroll
    for (int i = 0; i < 4; ++i) {
        int idx = base + i;
        if (idx < N) { rowptr[idx] = run; run += d[i]; }
    }
}

__global__ __launch_bounds__(256) void scatter_kernel(
    const int* __restrict__ src, const int* __restrict__ dst,
    const int* __restrict__ rowptr, int* __restrict__ cnt2,
    int2* __restrict__ edg, int E)
{
    const int i = blockIdx.x * 256 + threadIdx.x;
    if (i >= E) return;
    const int d = dst[i];
    const int pos = rowptr[d] + atomicAdd(&cnt2[d], 1);
    edg[pos] = make_int2(src[i], i);
}

// ------- fused per-node aggregation: fp8 kv, readlane broadcast, depth-2 pipeline -------
__global__ __launch_bounds__(256) void node_agg_kernel(
    const int2* __restrict__ edg, const int* __restrict__ rowptr,
    const float* __restrict__ ea,
    const bf16* __restrict__ q, const unsigned char* __restrict__ kv,
    const bf16* __restrict__ qWe,
    bf16* __restrict__ accV, bf16* __restrict__ aggEA, int N)
{
    const int w = threadIdx.x >> 6;
    const int lane = threadIdx.x & 63;
    const int d = blockIdx.x * 4 + w;
    if (d >= N) return;
    const int g = lane >> 4;     // head
    const int li = lane & 15;    // sub-lane: channels li*4..+3, features li*2..+1
    const int kvoff = (g * 16 + li) * 8;   // byte offset

    short4v qs = *(const short4v*)((const short*)q + (size_t)d * HC + g * C + li * 4);
    const float qv0 = bs2f(qs[0]), qv1 = bs2f(qs[1]), qv2 = bs2f(qs[2]), qv3 = bs2f(qs[3]);
    short2v qws = *(const short2v*)((const short*)qWe + (size_t)d * 128 + g * FE + li * 2);
    const float qw0 = bs2f(qws[0]), qw1 = bs2f(qws[1]);

    float den = 0.f;
    float a0 = 0.f, a1 = 0.f, a2 = 0.f, a3 = 0.f;
    float ag0 = 0.f, ag1 = 0.f;

    const int beg = rowptr[d];
    const int degc = rowptr[d + 1] - beg;

    for (int c0 = 0; c0 < degc; c0 += 64) {
        const int cnt = min(degc - c0, 64);
        int2 me = make_int2(0, 0);
        if (lane < cnt) me = edg[beg + c0 + lane];

        const int s0 = __builtin_amdgcn_readlane(me.x, 0);
        const int e0i = __builtin_amdgcn_readlane(me.y, 0);
        uint2 kvv = *(const uint2*)(kv + (size_t)s0 * 512 + kvoff);
        float2 eaf = *(const float2*)(ea + (size_t)e0i * FE + li * 2);

        for (int j = 0; j < cnt; ++j) {
            uint2 kvn = kvv; float2 ean = eaf;
            if (j + 1 < cnt) {
                const int sn = __builtin_amdgcn_readlane(me.x, j + 1);
                const int en = __builtin_amdgcn_readlane(me.y, j + 1);
                kvn = *(const uint2*)(kv + (size_t)sn * 512 + kvoff);
                ean = *(const float2*)(ea + (size_t)en * FE + li * 2);
            }
            const float ea0 = eaf.x, ea1 = eaf.y;
            const int klo = (int)kvv.x, vhi = (int)kvv.y;
            float p = qv0 * __builtin_amdgcn_cvt_f32_fp8(klo, 0)
                    + qv1 * __builtin_amdgcn_cvt_f32_fp8(klo, 1)
                    + qv2 * __builtin_amdgcn_cvt_f32_fp8(klo, 2)
                    + qv3 * __builtin_amdgcn_cvt_f32_fp8(klo, 3)
                    + qw0 * ea0 + qw1 * ea1;
            p += __shfl_xor(p, 1, 64);
            p += __shfl_xor(p, 2, 64);
            p += __shfl_xor(p, 4, 64);
            p += __shfl_xor(p, 8, 64);
            const float e = exp2f(p * 0.18033688f);  // exp(p/8)
            den += e;
            a0 += e * __builtin_amdgcn_cvt_f32_fp8(vhi, 0);
            a1 += e * __builtin_amdgcn_cvt_f32_fp8(vhi, 1);
            a2 += e * __builtin_amdgcn_cvt_f32_fp8(vhi, 2);
            a3 += e * __builtin_amdgcn_cvt_f32_fp8(vhi, 3);
            ag0 += e * ea0; ag1 += e * ea1;
            kvv = kvn; eaf = ean;
        }
    }

    const float inv = den > 0.f ? 0.25f / den : 0.f;
    a0 *= inv; a1 *= inv; a2 *= inv; a3 *= inv;
    a0 += __shfl_xor(a0, 16, 64); a0 += __shfl_xor(a0, 32, 64);
    a1 += __shfl_xor(a1, 16, 64); a1 += __shfl_xor(a1, 32, 64);
    a2 += __shfl_xor(a2, 16, 64); a2 += __shfl_xor(a2, 32, 64);
    a3 += __shfl_xor(a3, 16, 64); a3 += __shfl_xor(a3, 32, 64);
    if (g == 0) {
        short4v o;
        o[0] = f2bs(a0); o[1] = f2bs(a1); o[2] = f2bs(a2); o[3] = f2bs(a3);
        *(short4v*)((short*)accV + (size_t)d * C + li * 4) = o;
    }
    short2v so;
    so[0] = f2bs(ag0 * inv);
    so[1] = f2bs(ag1 * inv);
    *(short2v*)((short*)aggEA + (size_t)d * 128 + g * FE + li * 2) = so;
}

// ------- final: MFMA aggEA@Wet + epilogue + MFMA classifier -------
__global__ __launch_bounds__(256) void final_kernel(
    const bf16* __restrict__ aggEA, const bf16* __restrict__ accV,
    const bf16* __restrict__ skip,
    const short* __restrict__ Wet, const short* __restrict__ Wct,
    const float* __restrict__ scalev, const float* __restrict__ shiftv,
    const float* __restrict__ bc,
    float* __restrict__ out, int N)
{
    const int wid = threadIdx.x >> 6;
    const int lane = threadIdx.x & 63;
    const int n0 = blockIdx.x * 16;
    const int arow = lane & 15, agrp = lane >> 4;
    __shared__ short hs[16][72];   // bf16 h-tile, padded

    int nA = n0 + arow; if (nA >= N) nA = N - 1;
    const short* ap = (const short*)aggEA + (size_t)nA * 128 + agrp * 8;
    const int c0 = wid * 16;
    const int col = c0 + arow;
    const short* wp = Wet + (size_t)col * FIN + agrp * 8;
    floatx4 acc = {0.f, 0.f, 0.f, 0.f};
#pragma unroll
    for (int ks = 0; ks < 4; ++ks) {
        short8v a = *(const short8v*)(ap + ks * 32);
        short8v b = *(const short8v*)(wp + ks * 32);
        acc = __builtin_amdgcn_mfma_f32_16x16x32_bf16(a, b, acc, 0, 0, 0);
    }
    const float sc = scalev[col], sh = shiftv[col];
#pragma unroll
    for (int r = 0; r < 4; ++r) {
        const int row = agrp * 4 + r;
        int n = n0 + row; int nc = (n < N) ? n : (N - 1);
        float z = acc[r] + b2f(accV[(size_t)nc * C + col]) + b2f(skip[(size_t)nc * C + col]);
        z = fmaxf(z, 0.f);
        z = z * sc + sh;
        hs[row][col] = f2bs(z);
    }
    __syncthreads();

    if (wid == 0) {
        short8v ah[2], bh[2];
#pragma unroll
        for (int ks = 0; ks < 2; ++ks) {
#pragma unroll
            for (int j = 0; j < 8; ++j) ah[ks][j] = hs[arow][ks * 32 + agrp * 8 + j];
            bh[ks] = *(const short8v*)(Wct + (size_t)arow * C + ks * 32 + agrp * 8);
        }
        floatx4 co = {0.f, 0.f, 0.f, 0.f};
        co = __builtin_amdgcn_mfma_f32_16x16x32_bf16(ah[0], bh[0], co, 0, 0, 0);
        co = __builtin_amdgcn_mfma_f32_16x16x32_bf16(ah[1], bh[1], co, 0, 0, 0);
        const float bcv = bc[arow];
#pragma unroll
        for (int r = 0; r < 4; ++r) {
            const int n = n0 + agrp * 4 + r;
            if (n < N) out[(size_t)n * NCLS + arow] = co[r] + bcv;
        }
    }
}

extern "C" void kernel_launch(void* const* d_in, const int* in_sizes, int n_in,
                              void* d_out, int out_size, void* d_ws, size_t ws_size,
                              hipStream_t stream)
{
    const float* x     = (const float*)d_in[0];
    const int*   ei    = (const int*)d_in[1];
    const float* ea    = (const float*)d_in[2];
    const float* Wq    = (const float*)d_in[3];
    const float* bq    = (const float*)d_in[4];
    const float* Wk    = (const float*)d_in[5];
    const float* bk    = (const float*)d_in[6];
    const float* Wv    = (const float*)d_in[7];
    const float* bv    = (const float*)d_in[8];
    const float* We    = (const float*)d_in[9];
    const float* Wskip = (const float*)d_in[10];
    const float* bskip = (const float*)d_in[11];
    const float* gamma = (const float*)d_in[12];
    const float* beta  = (const float*)d_in[13];
    const float* rmean = (const float*)d_in[14];
    const float* rvar  = (const float*)d_in[15];
    const float* Wc    = (const float*)d_in[16];
    const float* bc    = (const float*)d_in[17];
    float* out = (float*)d_out;

    const int N = in_sizes[0] / FIN;
    const int E = in_sizes[2] / FE;
    const int* srcp = ei;
    const int* dstp = ei + E;
    const int nb = (N + 1023) / 1024;

    char* w = (char*)d_ws;
    size_t off = 0;
    auto alloc = [&](size_t bytes) { void* p = w + off; off += (bytes + 255) & ~255ull; return p; };
    bf16*  qb     = (bf16*)alloc((size_t)N * HC * sizeof(bf16));
    unsigned char* kvbuf = (unsigned char*)alloc((size_t)N * 512);
    bf16*  qWe    = (bf16*)alloc((size_t)N * 128 * sizeof(bf16));
    bf16*  skip   = (bf16*)alloc((size_t)N * C * sizeof(bf16));
    int*   deg    = (int*)alloc((size_t)N * sizeof(int));
    int*   rowptr = (int*)alloc((size_t)(N + 1) * sizeof(int));
    int*   cnt2   = (int*)alloc((size_t)N * sizeof(int));
    int*   partials = (int*)alloc(256 * sizeof(int));
    int2*  edg    = (int2*)alloc((size_t)E * sizeof(int2));
    bf16*  accV   = (bf16*)alloc((size_t)N * C * sizeof(bf16));
    bf16*  aggEA  = (bf16*)alloc((size_t)N * 128 * sizeof(bf16));
    short* Wt     = (short*)alloc((size_t)WCOLS * FIN * sizeof(short));
    float* bias   = (float*)alloc((size_t)WCOLS * sizeof(float));
    short* Wet    = (short*)alloc((size_t)C * FIN * sizeof(short));
    short* Wct    = (short*)alloc((size_t)NCLS * C * sizeof(short));
    float* scalev = (float*)alloc((size_t)C * sizeof(float));
    float* shiftv = (float*)alloc((size_t)C * sizeof(float));

    hipMemsetAsync(deg,  0, (size_t)N * sizeof(int), stream);
    hipMemsetAsync(cnt2, 0, (size_t)N * sizeof(int), stream);

    pack_w_kernel<<<WCOLS + 64 + NCLS + 1, 128, 0, stream>>>(
        Wq, Wk, Wv, We, Wskip, bq, bk, bv, bskip, gamma, beta, rmean, rvar, Wc,
        Wt, bias, Wet, Wct, scalev, shiftv);
    qkv_mfma_kernel<<<(N + 31) / 32, 256, 0, stream>>>(
        x, Wt, bias, qb, kvbuf, qWe, skip, dstp, deg, N, E);
    partial_kernel<<<nb, 256, 0, stream>>>(deg, partials, N);
    scan_partials_kernel<<<1, 256, 0, stream>>>(partials, rowptr, nb, N);
    write_rowptr_kernel<<<nb, 256, 0, stream>>>(deg, partials, rowptr, N);
    scatter_kernel<<<(E + 255) / 256, 256, 0, stream>>>(srcp, dstp, rowptr, cnt2, edg, E);
    node_agg_kernel<<<(N + 3) / 4, 256, 0, stream>>>(edg, rowptr, ea, qb, kvbuf, qWe, accV, aggEA, N);
    final_kernel<<<(N + 15) / 16, 256, 0, stream>>>(aggEA, accV, skip, Wet, Wct, scalev, shiftv, bc, out, N);
}

// Round 19
// 187.396 us; speedup vs baseline: 2.7735x; 1.0140x over previous
//
#include <hip/hip_runtime.h>
#include <hip/hip_bf16.h>

#define H 4
#define C 64
#define HC 256
#define FIN 128
#define FE 32
#define NCLS 16
#define BN_EPS 1e-5f
#define WCOLS 960   // 256 q | 256 k | 256 v | 128 qWe | 64 skip

typedef __hip_bfloat16 bf16;
typedef __attribute__((ext_vector_type(8))) short short8v;
typedef __attribute__((ext_vector_type(4))) short short4v;
typedef __attribute__((ext_vector_type(2))) short short2v;
typedef __attribute__((ext_vector_type(4))) float floatx4;

__device__ __forceinline__ float b2f(bf16 v) { return __bfloat162float(v); }
__device__ __forceinline__ float bs2f(short s) {
    unsigned u = ((unsigned)(unsigned short)s) << 16;
    return __uint_as_float(u);
}
__device__ __forceinline__ short f2bs(float f) {
    bf16 h = __float2bfloat16(f);
    return *reinterpret_cast<short*>(&h);
}

// ------- pack: Wt[960][128] bf16 + bias[960] + Wet[64][128] + Wct[16][64] + BN scale/shift -------
__global__ __launch_bounds__(128) void pack_w_kernel(
    const float* __restrict__ Wq, const float* __restrict__ Wk, const float* __restrict__ Wv,
    const float* __restrict__ We, const float* __restrict__ Wskip,
    const float* __restrict__ bq, const float* __restrict__ bk, const float* __restrict__ bv,
    const float* __restrict__ bskip,
    const float* __restrict__ gamma, const float* __restrict__ beta,
    const float* __restrict__ rmean, const float* __restrict__ rvar,
    const float* __restrict__ Wc,
    short* __restrict__ Wt, float* __restrict__ bias,
    short* __restrict__ Wet, short* __restrict__ Wct,
    float* __restrict__ scalev, float* __restrict__ shiftv)
{
    const int bid = blockIdx.x;
    const int t = threadIdx.x;       // 0..127
    if (bid < WCOLS) {
        const int col = bid;
        float val, b = 0.f;
        if (col < 256)      { val = Wq[t * HC + col]; b = bq[col]; }
        else if (col < 512) { val = Wk[t * HC + col - 256]; b = bk[col - 256]; }
        else if (col < 768) { val = Wv[t * HC + col - 512]; b = bv[col - 512]; }
        else if (col < 896) {
            int j = col - 768, h = j >> 5, f = j & 31;
            float acc = 0.f;
#pragma unroll 8
            for (int c = 0; c < C; ++c) acc += Wq[t * HC + h * C + c] * We[f * HC + h * C + c];
            val = acc;
            acc = 0.f;
            for (int c = 0; c < C; ++c) acc += bq[h * C + c] * We[f * HC + h * C + c];
            b = acc;
        }
        else { int c2 = col - 896; val = Wskip[t * C + c2]; b = bskip[c2]; }
        Wt[(size_t)col * FIN + t] = f2bs(val);
        if (t == 0) bias[col] = b;
    } else if (bid < WCOLS + 64) {
        const int c2 = bid - WCOLS;
        const int f = t & 31, h = t >> 5;
        Wet[(size_t)c2 * FIN + t] = f2bs(We[f * HC + h * C + c2]);
    } else if (bid < WCOLS + 64 + NCLS) {
        const int cls = bid - WCOLS - 64;
        if (t < C) Wct[(size_t)cls * C + t] = f2bs(Wc[t * NCLS + cls]);
    } else {
        if (t < C) {
            float inv = rsqrtf(rvar[t] + BN_EPS);
            float sc = gamma[t] * inv;
            scalev[t] = sc;
            shiftv[t] = beta[t] - rmean[t] * sc;
        }
    }
}

// ------- MFMA: [N,128] x Wt[960,128]^T ; 32 rows/block + fused hist epilogue -------
__global__ __launch_bounds__(256) void qkv_mfma_kernel(
    const float* __restrict__ x, const short* __restrict__ Wt,
    const float* __restrict__ bias,
    bf16* __restrict__ q, unsigned char* __restrict__ kv,
    bf16* __restrict__ qWe, bf16* __restrict__ skip,
    const int* __restrict__ dst, int* __restrict__ deg, int N, int E)
{
    const int wid = threadIdx.x >> 6;
    const int lane = threadIdx.x & 63;
    const int n0 = blockIdx.x * 32;
    const int arow = lane & 15, agrp = lane >> 4;
    __shared__ __align__(16) unsigned char kvs[32][512];

    short8v afrag[2][4];
#pragma unroll
    for (int rt = 0; rt < 2; ++rt) {
        int nA = n0 + rt * 16 + arow; if (nA >= N) nA = N - 1;
        const float* xrow = x + (size_t)nA * FIN + agrp * 8;
#pragma unroll
        for (int ks = 0; ks < 4; ++ks) {
            floatx4 x0 = *(const floatx4*)(xrow + ks * 32);
            floatx4 x1 = *(const floatx4*)(xrow + ks * 32 + 4);
            short8v a;
            a[0] = f2bs(x0[0]); a[1] = f2bs(x0[1]); a[2] = f2bs(x0[2]); a[3] = f2bs(x0[3]);
            a[4] = f2bs(x1[0]); a[5] = f2bs(x1[1]); a[6] = f2bs(x1[2]); a[7] = f2bs(x1[3]);
            afrag[rt][ks] = a;
        }
    }

    for (int ct = wid; ct < WCOLS / 16; ct += 4) {
        const int col0 = ct * 16;
        const int col = col0 + arow;
        const short* wp = Wt + (size_t)col * FIN + agrp * 8;
        short8v bfr[4];
#pragma unroll
        for (int ks = 0; ks < 4; ++ks) bfr[ks] = *(const short8v*)(wp + ks * 32);
        floatx4 acc0 = {0.f, 0.f, 0.f, 0.f};
        floatx4 acc1 = {0.f, 0.f, 0.f, 0.f};
#pragma unroll
        for (int ks = 0; ks < 4; ++ks) {
            acc0 = __builtin_amdgcn_mfma_f32_16x16x32_bf16(afrag[0][ks], bfr[ks], acc0, 0, 0, 0);
            acc1 = __builtin_amdgcn_mfma_f32_16x16x32_bf16(afrag[1][ks], bfr[ks], acc1, 0, 0, 0);
        }
        const float bb = bias[col];
#pragma unroll
        for (int rt = 0; rt < 2; ++rt) {
            const floatx4 acc = rt ? acc1 : acc0;
#pragma unroll
            for (int r = 0; r < 4; ++r) {
                const int row = rt * 16 + agrp * 4 + r;
                const int n = n0 + row;
                const float val = acc[r] + bb;
                if (col0 >= 256 && col0 < 768) {
                    int c = col - 256;
                    const int isv = (c >= 256) ? 4 : 0;
                    c &= 255;
                    const int pos = ((c >> 6) * 16 + ((c & 63) >> 2)) * 8 + (c & 3) + isv;
                    const int p8 = __builtin_amdgcn_cvt_pk_fp8_f32(val, val, 0, false);
                    kvs[row][pos] = (unsigned char)(p8 & 0xff);
                } else if (n < N) {
                    if (col0 < 256)      q[(size_t)n * HC + col]          = __float2bfloat16(val);
                    else if (col0 < 896) qWe[(size_t)n * 128 + col - 768] = __float2bfloat16(val);
                    else                 skip[(size_t)n * C + col - 896]  = __float2bfloat16(val);
                }
            }
        }
    }
    __syncthreads();
    const int t = threadIdx.x;
#pragma unroll
    for (int it = 0; it < 4; ++it) {
        const int lin = it * 256 + t;      // 0..1023
        const int row = lin >> 5;          // 0..31
        const int ch  = lin & 31;          // 16B chunk within row
        const int n = n0 + row;
        if (n < N)
            *(uint4*)(kv + (size_t)n * 512 + ch * 16) = *(const uint4*)(&kvs[row][ch * 16]);
    }
    // fused hist: grid-stride over edges (independent of qkv outputs)
    const int gtid = blockIdx.x * 256 + t;
    const int nth = gridDim.x * 256;
    for (int i = gtid; i < E; i += nth) atomicAdd(&deg[dst[i]], 1);
}

// ------- CSR build: per-block partial sums -------
__global__ __launch_bounds__(256) void partial_kernel(
    const int* __restrict__ deg, int* __restrict__ partials, int N)
{
    const int t = threadIdx.x;
    const int base = blockIdx.x * 1024 + t * 4;
    int s = 0;
#pragma unroll
    for (int i = 0; i < 4; ++i) {
        int idx = base + i;
        if (idx < N) s += deg[idx];
    }
#pragma unroll
    for (int off = 1; off < 64; off <<= 1) s += __shfl_xor(s, off, 64);
    __shared__ int ws[4];
    if ((t & 63) == 0) ws[t >> 6] = s;
    __syncthreads();
    if (t == 0) partials[blockIdx.x] = ws[0] + ws[1] + ws[2] + ws[3];
}

// ------- merged: every block re-scans the (<=256) partials for its base, then writes rowptr -------
__global__ __launch_bounds__(256) void rowptr_kernel(
    const int* __restrict__ deg, const int* __restrict__ partials,
    int* __restrict__ rowptr, int nb, int N)
{
    const int t = threadIdx.x;
    __shared__ int sm[256];
    __shared__ int base_s;
    int v = (t < nb) ? partials[t] : 0;
    sm[t] = v;
    __syncthreads();
    for (int off = 1; off < 256; off <<= 1) {
        int vv = (t >= off) ? sm[t - off] : 0;
        __syncthreads();
        sm[t] += vv;
        __syncthreads();
    }
    if (t == 0) base_s = (blockIdx.x == 0) ? 0 : sm[blockIdx.x - 1];
    if (blockIdx.x == 0 && t == 0) rowptr[N] = sm[nb - 1];
    __syncthreads();
    const int blockbase = base_s;
    __syncthreads();   // sm reuse barrier

    const int base = blockIdx.x * 1024 + t * 4;
    int d[4];
    int s = 0;
#pragma unroll
    for (int i = 0; i < 4; ++i) {
        int idx = base + i;
        d[i] = (idx < N) ? deg[idx] : 0;
        s += d[i];
    }
    sm[t] = s;
    __syncthreads();
    for (int off = 1; off < 256; off <<= 1) {
        int vv = (t >= off) ? sm[t - off] : 0;
        __syncthreads();
        sm[t] += vv;
        __syncthreads();
    }
    int run = blockbase + sm[t] - s;
#pragma unroll
    for (int i = 0; i < 4; ++i) {
        int idx = base + i;
        if (idx < N) { rowptr[idx] = run; run += d[i]; }
    }
}

__global__ __launch_bounds__(256) void scatter_kernel(
    const int* __restrict__ src, const int* __restrict__ dst,
    const int* __restrict__ rowptr, int* __restrict__ cnt2,
    int2* __restrict__ edg, int E)
{
    const int i = blockIdx.x * 256 + threadIdx.x;
    if (i >= E) return;
    const int d = dst[i];
    const int pos = rowptr[d] + atomicAdd(&cnt2[d], 1);
    edg[pos] = make_int2(src[i], i);
}

// ------- fused per-node aggregation: fp8 kv, readlane broadcast, depth-2 pipeline -------
__global__ __launch_bounds__(256) void node_agg_kernel(
    const int2* __restrict__ edg, const int* __restrict__ rowptr,
    const float* __restrict__ ea,
    const bf16* __restrict__ q, const unsigned char* __restrict__ kv,
    const bf16* __restrict__ qWe,
    bf16* __restrict__ accV, bf16* __restrict__ aggEA, int N)
{
    const int w = threadIdx.x >> 6;
    const int lane = threadIdx.x & 63;
    const int d = blockIdx.x * 4 + w;
    if (d >= N) return;
    const int g = lane >> 4;     // head
    const int li = lane & 15;    // sub-lane: channels li*4..+3, features li*2..+1
    const int kvoff = (g * 16 + li) * 8;   // byte offset

    short4v qs = *(const short4v*)((const short*)q + (size_t)d * HC + g * C + li * 4);
    const float qv0 = bs2f(qs[0]), qv1 = bs2f(qs[1]), qv2 = bs2f(qs[2]), qv3 = bs2f(qs[3]);
    short2v qws = *(const short2v*)((const short*)qWe + (size_t)d * 128 + g * FE + li * 2);
    const float qw0 = bs2f(qws[0]), qw1 = bs2f(qws[1]);

    float den = 0.f;
    float a0 = 0.f, a1 = 0.f, a2 = 0.f, a3 = 0.f;
    float ag0 = 0.f, ag1 = 0.f;

    const int beg = rowptr[d];
    const int degc = rowptr[d + 1] - beg;

    for (int c0 = 0; c0 < degc; c0 += 64) {
        const int cnt = min(degc - c0, 64);
        int2 me = make_int2(0, 0);
        if (lane < cnt) me = edg[beg + c0 + lane];

        const int s0 = __builtin_amdgcn_readlane(me.x, 0);
        const int e0i = __builtin_amdgcn_readlane(me.y, 0);
        uint2 kvv = *(const uint2*)(kv + (size_t)s0 * 512 + kvoff);
        float2 eaf = *(const float2*)(ea + (size_t)e0i * FE + li * 2);

        for (int j = 0; j < cnt; ++j) {
            uint2 kvn = kvv; float2 ean = eaf;
            if (j + 1 < cnt) {
                const int sn = __builtin_amdgcn_readlane(me.x, j + 1);
                const int en = __builtin_amdgcn_readlane(me.y, j + 1);
                kvn = *(const uint2*)(kv + (size_t)sn * 512 + kvoff);
                ean = *(const float2*)(ea + (size_t)en * FE + li * 2);
            }
            const float ea0 = eaf.x, ea1 = eaf.y;
            const int klo = (int)kvv.x, vhi = (int)kvv.y;
            float p = qv0 * __builtin_amdgcn_cvt_f32_fp8(klo, 0)
                    + qv1 * __builtin_amdgcn_cvt_f32_fp8(klo, 1)
                    + qv2 * __builtin_amdgcn_cvt_f32_fp8(klo, 2)
                    + qv3 * __builtin_amdgcn_cvt_f32_fp8(klo, 3)
                    + qw0 * ea0 + qw1 * ea1;
            p += __shfl_xor(p, 1, 64);
            p += __shfl_xor(p, 2, 64);
            p += __shfl_xor(p, 4, 64);
            p += __shfl_xor(p, 8, 64);
            const float e = exp2f(p * 0.18033688f);  // exp(p/8)
            den += e;
            a0 += e * __builtin_amdgcn_cvt_f32_fp8(vhi, 0);
            a1 += e * __builtin_amdgcn_cvt_f32_fp8(vhi, 1);
            a2 += e * __builtin_amdgcn_cvt_f32_fp8(vhi, 2);
            a3 += e * __builtin_amdgcn_cvt_f32_fp8(vhi, 3);
            ag0 += e * ea0; ag1 += e * ea1;
            kvv = kvn; eaf = ean;
        }
    }

    const float inv = den > 0.f ? 0.25f / den : 0.f;
    a0 *= inv; a1 *= inv; a2 *= inv; a3 *= inv;
    a0 += __shfl_xor(a0, 16, 64); a0 += __shfl_xor(a0, 32, 64);
    a1 += __shfl_xor(a1, 16, 64); a1 += __shfl_xor(a1, 32, 64);
    a2 += __shfl_xor(a2, 16, 64); a2 += __shfl_xor(a2, 32, 64);
    a3 += __shfl_xor(a3, 16, 64); a3 += __shfl_xor(a3, 32, 64);
    if (g == 0) {
        short4v o;
        o[0] = f2bs(a0); o[1] = f2bs(a1); o[2] = f2bs(a2); o[3] = f2bs(a3);
        *(short4v*)((short*)accV + (size_t)d * C + li * 4) = o;
    }
    short2v so;
    so[0] = f2bs(ag0 * inv);
    so[1] = f2bs(ag1 * inv);
    *(short2v*)((short*)aggEA + (size_t)d * 128 + g * FE + li * 2) = so;
}

// ------- final: MFMA aggEA@Wet + epilogue + MFMA classifier -------
__global__ __launch_bounds__(256) void final_kernel(
    const bf16* __restrict__ aggEA, const bf16* __restrict__ accV,
    const bf16* __restrict__ skip,
    const short* __restrict__ Wet, const short* __restrict__ Wct,
    const float* __restrict__ scalev, const float* __restrict__ shiftv,
    const float* __restrict__ bc,
    float* __restrict__ out, int N)
{
    const int wid = threadIdx.x >> 6;
    const int lane = threadIdx.x & 63;
    const int n0 = blockIdx.x * 16;
    const int arow = lane & 15, agrp = lane >> 4;
    __shared__ short hs[16][72];   // bf16 h-tile, padded

    int nA = n0 + arow; if (nA >= N) nA = N - 1;
    const short* ap = (const short*)aggEA + (size_t)nA * 128 + agrp * 8;
    const int c0 = wid * 16;
    const int col = c0 + arow;
    const short* wp = Wet + (size_t)col * FIN + agrp * 8;
    floatx4 acc = {0.f, 0.f, 0.f, 0.f};
#pragma unroll
    for (int ks = 0; ks < 4; ++ks) {
        short8v a = *(const short8v*)(ap + ks * 32);
        short8v b = *(const short8v*)(wp + ks * 32);
        acc = __builtin_amdgcn_mfma_f32_16x16x32_bf16(a, b, acc, 0, 0, 0);
    }
    const float sc = scalev[col], sh = shiftv[col];
#pragma unroll
    for (int r = 0; r < 4; ++r) {
        const int row = agrp * 4 + r;
        int n = n0 + row; int nc = (n < N) ? n : (N - 1);
        float z = acc[r] + b2f(accV[(size_t)nc * C + col]) + b2f(skip[(size_t)nc * C + col]);
        z = fmaxf(z, 0.f);
        z = z * sc + sh;
        hs[row][col] = f2bs(z);
    }
    __syncthreads();

    if (wid == 0) {
        short8v ah[2], bh[2];
#pragma unroll
        for (int ks = 0; ks < 2; ++ks) {
#pragma unroll
            for (int j = 0; j < 8; ++j) ah[ks][j] = hs[arow][ks * 32 + agrp * 8 + j];
            bh[ks] = *(const short8v*)(Wct + (size_t)arow * C + ks * 32 + agrp * 8);
        }
        floatx4 co = {0.f, 0.f, 0.f, 0.f};
        co = __builtin_amdgcn_mfma_f32_16x16x32_bf16(ah[0], bh[0], co, 0, 0, 0);
        co = __builtin_amdgcn_mfma_f32_16x16x32_bf16(ah[1], bh[1], co, 0, 0, 0);
        const float bcv = bc[arow];
#pragma unroll
        for (int r = 0; r < 4; ++r) {
            const int n = n0 + agrp * 4 + r;
            if (n < N) out[(size_t)n * NCLS + arow] = co[r] + bcv;
        }
    }
}

extern "C" void kernel_launch(void* const* d_in, const int* in_sizes, int n_in,
                              void* d_out, int out_size, void* d_ws, size_t ws_size,
                              hipStream_t stream)
{
    const float* x     = (const float*)d_in[0];
    const int*   ei    = (const int*)d_in[1];
    const float* ea    = (const float*)d_in[2];
    const float* Wq    = (const float*)d_in[3];
    const float* bq    = (const float*)d_in[4];
    const float* Wk    = (const float*)d_in[5];
    const float* bk    = (const float*)d_in[6];
    const float* Wv    = (const float*)d_in[7];
    const float* bv    = (const float*)d_in[8];
    const float* We    = (const float*)d_in[9];
    const float* Wskip = (const float*)d_in[10];
    const float* bskip = (const float*)d_in[11];
    const float* gamma = (const float*)d_in[12];
    const float* beta  = (const float*)d_in[13];
    const float* rmean = (const float*)d_in[14];
    const float* rvar  = (const float*)d_in[15];
    const float* Wc    = (const float*)d_in[16];
    const float* bc    = (const float*)d_in[17];
    float* out = (float*)d_out;

    const int N = in_sizes[0] / FIN;
    const int E = in_sizes[2] / FE;
    const int* srcp = ei;
    const int* dstp = ei + E;
    const int nb = (N + 1023) / 1024;

    char* w = (char*)d_ws;
    size_t off = 0;
    auto alloc = [&](size_t bytes) { void* p = w + off; off += (bytes + 255) & ~255ull; return p; };
    bf16*  qb     = (bf16*)alloc((size_t)N * HC * sizeof(bf16));
    unsigned char* kvbuf = (unsigned char*)alloc((size_t)N * 512);
    bf16*  qWe    = (bf16*)alloc((size_t)N * 128 * sizeof(bf16));
    bf16*  skip   = (bf16*)alloc((size_t)N * C * sizeof(bf16));
    int*   deg    = (int*)alloc((size_t)(2 * N) * sizeof(int));   // deg[N] + cnt2[N] adjacent, single memset
    int*   cnt2   = deg + N;
    int*   rowptr = (int*)alloc((size_t)(N + 1) * sizeof(int));
    int*   partials = (int*)alloc(256 * sizeof(int));
    int2*  edg    = (int2*)alloc((size_t)E * sizeof(int2));
    bf16*  accV   = (bf16*)alloc((size_t)N * C * sizeof(bf16));
    bf16*  aggEA  = (bf16*)alloc((size_t)N * 128 * sizeof(bf16));
    short* Wt     = (short*)alloc((size_t)WCOLS * FIN * sizeof(short));
    float* bias   = (float*)alloc((size_t)WCOLS * sizeof(float));
    short* Wet    = (short*)alloc((size_t)C * FIN * sizeof(short));
    short* Wct    = (short*)alloc((size_t)NCLS * C * sizeof(short));
    float* scalev = (float*)alloc((size_t)C * sizeof(float));
    float* shiftv = (float*)alloc((size_t)C * sizeof(float));

    hipMemsetAsync(deg, 0, (size_t)(2 * N) * sizeof(int), stream);

    pack_w_kernel<<<WCOLS + 64 + NCLS + 1, 128, 0, stream>>>(
        Wq, Wk, Wv, We, Wskip, bq, bk, bv, bskip, gamma, beta, rmean, rvar, Wc,
        Wt, bias, Wet, Wct, scalev, shiftv);
    qkv_mfma_kernel<<<(N + 31) / 32, 256, 0, stream>>>(
        x, Wt, bias, qb, kvbuf, qWe, skip, dstp, deg, N, E);
    partial_kernel<<<nb, 256, 0, stream>>>(deg, partials, N);
    rowptr_kernel<<<nb, 256, 0, stream>>>(deg, partials, rowptr, nb, N);
    scatter_kernel<<<(E + 255) / 256, 256, 0, stream>>>(srcp, dstp, rowptr, cnt2, edg, E);
    node_agg_kernel<<<(N + 3) / 4, 256, 0, stream>>>(edg, rowptr, ea, qb, kvbuf, qWe, accV, aggEA, N);
    final_kernel<<<(N + 15) / 16, 256, 0, stream>>>(aggEA, accV, skip, Wet, Wct, scalev, shiftv, bc, out, N);
}